// Round 22
// baseline (61.010 us; speedup 1.0000x reference)
//
#include <hip/hip_runtime.h>
#include <math.h>

#define LAM 0.01f

typedef __bf16 bf16x8 __attribute__((ext_vector_type(8)));
typedef float f32x4 __attribute__((ext_vector_type(4)));
typedef short short8v __attribute__((ext_vector_type(8)));
typedef short short4v __attribute__((ext_vector_type(4)));
typedef unsigned int uint4v __attribute__((ext_vector_type(4)));

#define BF(v) __builtin_bit_cast(bf16x8, (v))
#define MFMA __builtin_amdgcn_mfma_f32_16x16x32_bf16
#define XROW 36   // xs row stride in shorts (72B): lg-groups land 2-way (free)
#define LDS_FENCE() do { asm volatile("s_waitcnt lgkmcnt(0)" ::: "memory"); \
                         __builtin_amdgcn_sched_barrier(0); } while (0)
// packed f32x2 -> bf16x2 in one dword: kills sub-dword insert traffic
#define CVTPK(d, lo, hi) asm("v_cvt_pk_bf16_f32 %0, %1, %2" : "=v"(d) : "v"(lo), "v"(hi))

__device__ __forceinline__ unsigned short f2bf(float f) {
    __bf16 h = (__bf16)f;
    return __builtin_bit_cast(unsigned short, h);
}
__device__ __forceinline__ float bf2f(unsigned short u) {
    unsigned int v = ((unsigned int)u) << 16;
    return __builtin_bit_cast(float, v);
}

// 188 wave-tasks/(b,n), tau = (block_w<<2)|wv. sh = 9-log2(P); twiddles in
// 512-space. jump_s is EXCLUSIVE of t_lo (covers s < t_lo): every steady step
// does an update -> uniform 8 STEP2 pairs per 16-step segment.
// Mega P=512 tasks cover 2 chunks each (16 tasks).
struct Task { int sh, c16, t_lo, t_hi, jump_s; };
__device__ __forceinline__ Task task_params(int tau) {
    Task tk;
    if (tau < 16)       { tk.sh = 0; tk.c16 = tau * 2; tk.t_lo = 255; tk.t_hi = 255; tk.jump_s = 256; }   // P=512 mega2
    else if (tau < 144) { int u = tau - 16;  int seg = u >> 4; tk.sh = 1; tk.c16 = u & 15;
                          tk.t_lo = 127 + 16 * seg; tk.t_hi = tk.t_lo + 15; tk.jump_s = tk.t_lo; }        // P=256
    else if (tau < 176) { int u = tau - 144; int seg = u >> 3; tk.sh = 2; tk.c16 = u & 7;
                          tk.t_lo = 63 + 16 * seg; tk.t_hi = tk.t_lo + 15; tk.jump_s = tk.t_lo; }         // P=128
    else if (tau < 184) { int u = tau - 176; int seg = u >> 2; tk.sh = 3; tk.c16 = u & 3;
                          tk.t_lo = 31 + 16 * seg; tk.t_hi = tk.t_lo + 15; tk.jump_s = tk.t_lo; }         // P=64
    else if (tau < 186) { tk.sh = 4; tk.c16 = tau - 184; tk.t_lo = 15; tk.t_hi = 30; tk.jump_s = 0; }     // P=32
    else if (tau == 186){ tk.sh = 5; tk.c16 = 0; tk.t_lo = 7; tk.t_hi = 14; tk.jump_s = 0; }              // P=16
    else                { tk.sh = 6; tk.c16 = 0; tk.t_lo = 0; tk.t_hi = 6;  tk.jump_s = 0; }              // P=8
    return tk;
}

// MFMA layouts (m89-verified). Layer1 transposed; layer-1 output channels
// permuted so C regs ARE the layer-2 A-fragment (r10). STEP2 = 2 independent
// fence-free chains (r19; STEP4 spilled, r20). invSqrtP folded into W1 fwd /
// W2+b2 inv (softshrink(ax,aL)=a*softshrink(x,L)). r22: SNAP/REPACK build
// fragments via v_cvt_pk_bf16_f32 dword writes -- r21 disasm arithmetic showed
// ~3x VALU bloat vs hand count, consistent with per-element vector inserts.
__global__ __launch_bounds__(256, 3)
void afno_mfma(const float* __restrict__ x,
               const float* __restrict__ w1,
               const float* __restrict__ b1,
               const float* __restrict__ w2,
               const float* __restrict__ b2,
               float* __restrict__ out) {
    __shared__ unsigned short xs[256 * XROW];  // raw bf16 x, stride-padded  18 KB
    __shared__ float2 tw[544];                 // (cos,sin)(2pi m/512), idx m+(m>>4)
    __shared__ float jslab[4 * 544];           // per-wave f32 [16][33] jump slab

    int bid = blockIdx.x;
    int w  = bid >> 5;                    // 0..46
    int bn = bid & 31;
    int b = bn >> 3, n = bn & 7;

    int tid = threadIdx.x;
    int wv = tid >> 6;
    int lane = tid & 63;
    int lg = lane >> 4;
    int l15 = lane & 15;
    int krow = lg * 8;

    // ---- stage x rows (raw bf16, rows padded to a 32-multiple) + twiddles ----
    int rows = 0;
    #pragma unroll
    for (int q = 0; q < 4; ++q) {
        Task t2 = task_params((w << 2) | q);
        rows = rows > (t2.t_hi + 1) ? rows : (t2.t_hi + 1);
    }
    rows = (rows + 31) & ~31;
    rows = rows > 256 ? 256 : rows;
    for (int idx = tid; idx < rows * 16; idx += 256) {
        int row = idx >> 4, cp = idx & 15;
        float2 v = *(const float2*)(x + (b * 256 + row) * 256 + n * 32 + cp * 2);
        unsigned int pk;
        CVTPK(pk, v.x, v.y);
        *(unsigned int*)(xs + row * XROW + cp * 2) = pk;
    }
    for (int m = tid; m < 512; m += 256) {
        float sv, cv;
        sincosf(6.28318530717958647692f * (float)m * (1.0f / 512.0f), &sv, &cv);
        tw[m + (m >> 4)] = make_float2(cv, sv);
    }

    Task tk = task_params((w << 2) | wv);
    int P = 512 >> tk.sh;
    float invSqrtP = rsqrtf((float)P);
    float LAMe = LAM * invSqrtP;          // effective softshrink threshold

    // ---- weights -> bf16 fragments; W1 carries forward 1/sqrt(P), W2/b2 carry
    //      inverse 1/sqrt(P); W2 rows in chan-permuted order ----
    const float* w1r = w1 + n * 1024;
    const float* w1i = w1 + (8 + n) * 1024;
    const float* w2r = w2 + n * 1024;
    const float* w2i = w2 + (8 + n) * 1024;
    short8v W10[2], W11[2], W11n[2], W20[2], W21[2], W21n[2];
    #pragma unroll
    for (int h = 0; h < 2; ++h) {
        int col = h * 16 + l15;
        #pragma unroll
        for (int j = 0; j < 8; ++j) {
            W10[h][j]  = (short)f2bf(w1r[(krow + j) * 32 + col] * invSqrtP);
            W11[h][j]  = (short)f2bf(w1i[(krow + j) * 32 + col] * invSqrtP);
            W11n[h][j] = W11[h][j] ^ (short)0x8000;
            int crow = ((j >> 2) * 16) + (lg * 4) + (j & 3);   // chan permutation
            W20[h][j]  = (short)f2bf(w2r[crow * 32 + col] * invSqrtP);
            W21[h][j]  = (short)f2bf(w2i[crow * 32 + col] * invSqrtP);
            W21n[h][j] = W21[h][j] ^ (short)0x8000;
        }
    }
    f32x4 b1rv[2], b1iv[2];
    float b2r_[2], b2i_[2];
    #pragma unroll
    for (int h = 0; h < 2; ++h) {
        int base = n * 32 + h * 16 + lg * 4;
        b1rv[h] = f32x4{b1[base], b1[base + 1], b1[base + 2], b1[base + 3]};
        b1iv[h] = f32x4{b1[256 + base], b1[256 + base + 1], b1[256 + base + 2], b1[256 + base + 3]};
        b2r_[h] = b2[n * 32 + h * 16 + l15] * invSqrtP;
        b2i_[h] = b2[256 + n * 32 + h * 16 + l15] * invSqrtP;
    }
    __syncthreads();   // only block barrier

    int pA5 = 0, mA5 = 0;
    int prow5[4], mrow5[4];
    float Xre[8] = {0,0,0,0,0,0,0,0}, Xim[8] = {0,0,0,0,0,0,0,0};

// Prefix jump via MFMA: X = sum_{s < js_} e^{-i th} x[s]. Per-j validity mask.
#define JUMP_X(js_) do { \
        f32x4 jre0 = {0,0,0,0}, jre1 = {0,0,0,0}, jim0 = {0,0,0,0}, jim1 = {0,0,0,0}; \
        int nkk_ = ((js_) + 31) >> 5; \
        for (int kk = 0; kk < nkk_; ++kk) { \
            int sb_ = kk * 32; \
            short8v ac_, an2_; \
            int mj_ = (pA5 * (sb_ + krow)) & 511; \
            _Pragma("unroll") \
            for (int j = 0; j < 8; ++j) { \
                int mi2_ = mj_ + (mj_ >> 4); \
                float2 t_ = tw[mi2_]; \
                bool ok_ = (sb_ + krow + j) < (js_); \
                ac_[j]  = ok_ ? (short)f2bf(t_.x)  : (short)0; \
                an2_[j] = ok_ ? (short)f2bf(-t_.y) : (short)0; \
                mj_ = (mj_ + pA5) & 511; \
            } \
            short8v bx0_, bx1_; \
            _Pragma("unroll") \
            for (int j = 0; j < 8; ++j) { \
                int base_ = (sb_ + krow + j) * XROW + l15; \
                bx0_[j] = (short)xs[base_]; \
                bx1_[j] = (short)xs[base_ + 16]; \
            } \
            jre0 = MFMA(BF(ac_),  BF(bx0_), jre0, 0, 0, 0); \
            jim0 = MFMA(BF(an2_), BF(bx0_), jim0, 0, 0, 0); \
            jre1 = MFMA(BF(ac_),  BF(bx1_), jre1, 0, 0, 0); \
            jim1 = MFMA(BF(an2_), BF(bx1_), jim1, 0, 0, 0); \
        } \
        float* jt_ = jslab + wv * 544; \
        _Pragma("unroll") \
        for (int r = 0; r < 4; ++r) { \
            jt_[(lg * 4 + r) * 33 + l15]      = jre0[r]; \
            jt_[(lg * 4 + r) * 33 + 16 + l15] = jre1[r]; \
        } \
        LDS_FENCE(); \
        _Pragma("unroll") \
        for (int j = 0; j < 8; ++j) Xre[j] = jt_[l15 * 33 + krow + j]; \
        LDS_FENCE(); \
        _Pragma("unroll") \
        for (int r = 0; r < 4; ++r) { \
            jt_[(lg * 4 + r) * 33 + l15]      = jim0[r]; \
            jt_[(lg * 4 + r) * 33 + 16 + l15] = jim1[r]; \
        } \
        LDS_FENCE(); \
        _Pragma("unroll") \
        for (int j = 0; j < 8; ++j) Xim[j] = jt_[l15 * 33 + krow + j]; \
        LDS_FENCE(); \
    } while (0)

#define UPDATE_X(sidx) do { \
        int mi_ = mA5 + (mA5 >> 4); \
        float2 t_ = tw[mi_]; \
        mA5 = (mA5 + pA5) & 511; \
        short4v xa_ = *(const short4v*)(xs + (sidx) * XROW + krow); \
        short4v xb_ = *(const short4v*)(xs + (sidx) * XROW + krow + 4); \
        _Pragma("unroll") \
        for (int j = 0; j < 4; ++j) { \
            float xf = bf2f((unsigned short)xa_[j]); \
            Xre[j] = fmaf(xf, t_.x, Xre[j]); \
            Xim[j] = fmaf(xf, -t_.y, Xim[j]); \
            float xg = bf2f((unsigned short)xb_[j]); \
            Xre[4 + j] = fmaf(xg, t_.x, Xre[4 + j]); \
            Xim[4 + j] = fmaf(xg, -t_.y, Xim[4 + j]); \
        } } while (0)

// fragment build via packed converts: 8 cvt_pk, zero sub-dword inserts
#define SNAP_A(arv, aiv) do { \
        uint4v ur_, ui_; \
        CVTPK(ur_.x, Xre[0], Xre[1]); \
        CVTPK(ur_.y, Xre[2], Xre[3]); \
        CVTPK(ur_.z, Xre[4], Xre[5]); \
        CVTPK(ur_.w, Xre[6], Xre[7]); \
        CVTPK(ui_.x, Xim[0], Xim[1]); \
        CVTPK(ui_.y, Xim[2], Xim[3]); \
        CVTPK(ui_.z, Xim[4], Xim[5]); \
        CVTPK(ui_.w, Xim[6], Xim[7]); \
        (arv) = __builtin_bit_cast(short8v, ur_); \
        (aiv) = __builtin_bit_cast(short8v, ui_); \
    } while (0)

#define L1(arv, aiv, o1r_, o1i_) do { \
        _Pragma("unroll") \
        for (int h = 0; h < 2; ++h) { \
            o1r_[h] = MFMA(BF(arv), BF(W10[h]),  b1rv[h], 0, 0, 0); \
            o1r_[h] = MFMA(BF(aiv), BF(W11n[h]), o1r_[h], 0, 0, 0); \
            o1i_[h] = MFMA(BF(aiv), BF(W10[h]),  b1iv[h], 0, 0, 0); \
            o1i_[h] = MFMA(BF(arv), BF(W11[h]),  o1i_[h], 0, 0, 0); \
        } } while (0)

// relu + packed convert (chan-permuted rows already match dword layout:
// dword k = (o1_[k>>1][2*(k&1)], o1_[k>>1][2*(k&1)+1]))
#define REPACK(o1r_, o1i_, a2r_, a2i_) do { \
        uint4v ur_, ui_; \
        CVTPK(ur_.x, fmaxf(o1r_[0][0], 0.f), fmaxf(o1r_[0][1], 0.f)); \
        CVTPK(ur_.y, fmaxf(o1r_[0][2], 0.f), fmaxf(o1r_[0][3], 0.f)); \
        CVTPK(ur_.z, fmaxf(o1r_[1][0], 0.f), fmaxf(o1r_[1][1], 0.f)); \
        CVTPK(ur_.w, fmaxf(o1r_[1][2], 0.f), fmaxf(o1r_[1][3], 0.f)); \
        CVTPK(ui_.x, fmaxf(o1i_[0][0], 0.f), fmaxf(o1i_[0][1], 0.f)); \
        CVTPK(ui_.y, fmaxf(o1i_[0][2], 0.f), fmaxf(o1i_[0][3], 0.f)); \
        CVTPK(ui_.z, fmaxf(o1i_[1][0], 0.f), fmaxf(o1i_[1][1], 0.f)); \
        CVTPK(ui_.w, fmaxf(o1i_[1][2], 0.f), fmaxf(o1i_[1][3], 0.f)); \
        (a2r_) = __builtin_bit_cast(short8v, ur_); \
        (a2i_) = __builtin_bit_cast(short8v, ui_); \
    } while (0)

#define L2(a2r_, a2i_, o2r_, o2i_) do { \
        _Pragma("unroll") \
        for (int h = 0; h < 2; ++h) { \
            f32x4 cr = {b2r_[h], b2r_[h], b2r_[h], b2r_[h]}; \
            f32x4 ci = {b2i_[h], b2i_[h], b2i_[h], b2i_[h]}; \
            o2r_[h] = MFMA(BF(a2r_), BF(W20[h]),  cr, 0, 0, 0); \
            o2r_[h] = MFMA(BF(a2i_), BF(W21n[h]), o2r_[h], 0, 0, 0); \
            o2i_[h] = MFMA(BF(a2i_), BF(W20[h]),  ci, 0, 0, 0); \
            o2i_[h] = MFMA(BF(a2r_), BF(W21[h]),  o2i_[h], 0, 0, 0); \
        } } while (0)

// epilogue (softshrink with LAMe; inverse norm pre-folded into W2/b2)
#define EPI(o2r_, o2i_, tR, DEST) do { \
        float sh0 = 0.f, sh1 = 0.f; \
        _Pragma("unroll") \
        for (int r = 0; r < 4; ++r) { \
            float v0r = o2r_[0][r]; v0r -= __builtin_amdgcn_fmed3f(v0r, -LAMe, LAMe); \
            float v0i = o2i_[0][r]; v0i -= __builtin_amdgcn_fmed3f(v0i, -LAMe, LAMe); \
            sh0 = fmaf(v0r, (tR)[r].x, sh0); sh0 = fmaf(-v0i, (tR)[r].y, sh0); \
            float v1r = o2r_[1][r]; v1r -= __builtin_amdgcn_fmed3f(v1r, -LAMe, LAMe); \
            float v1i = o2i_[1][r]; v1i -= __builtin_amdgcn_fmed3f(v1i, -LAMe, LAMe); \
            sh1 = fmaf(v1r, (tR)[r].x, sh1); sh1 = fmaf(-v1i, (tR)[r].y, sh1); \
        } \
        sh0 += __shfl_xor(sh0, 16); \
        sh1 += __shfl_xor(sh1, 16); \
        if (P > 8) { sh0 += __shfl_xor(sh0, 32); sh1 += __shfl_xor(sh1, 32); } \
        DEST = (lane & 16) ? sh1 : sh0; \
    } while (0)

#define STEP1(sidx, do_upd) do { \
        if (do_upd) UPDATE_X(sidx); \
        short8v ar_, ai_, a2r_, a2i_; \
        SNAP_A(ar_, ai_); \
        f32x4 o1r_[2], o1i_[2], o2r_[2], o2i_[2]; \
        L1(ar_, ai_, o1r_, o1i_); \
        REPACK(o1r_, o1i_, a2r_, a2i_); \
        L2(a2r_, a2i_, o2r_, o2i_); \
        float2 tR[4]; \
        _Pragma("unroll") \
        for (int r = 0; r < 4; ++r) { \
            int mi_ = mrow5[r] + (mrow5[r] >> 4); \
            tR[r] = tw[mi_]; \
            mrow5[r] = (mrow5[r] + prow5[r]) & 511; \
        } \
        float v_; \
        EPI(o2r_, o2i_, tR, v_); \
        if (lane < 32) \
            atomicAdd(out + (b * 256 + (sidx)) * 256 + n * 32 + (lane & 31), v_); \
    } while (0)

// two independent chains, fence-free; atomics at the end (r19 sweet spot)
#define STEP2(s0) do { \
        short8v ar0_, ai0_, ar1_, ai1_, a2r0_, a2i0_, a2r1_, a2i1_; \
        UPDATE_X(s0);     SNAP_A(ar0_, ai0_); \
        UPDATE_X((s0)+1); SNAP_A(ar1_, ai1_); \
        f32x4 o1r0_[2], o1i0_[2], o1r1_[2], o1i1_[2]; \
        L1(ar0_, ai0_, o1r0_, o1i0_); \
        L1(ar1_, ai1_, o1r1_, o1i1_); \
        REPACK(o1r0_, o1i0_, a2r0_, a2i0_); \
        REPACK(o1r1_, o1i1_, a2r1_, a2i1_); \
        f32x4 o2r0_[2], o2i0_[2], o2r1_[2], o2i1_[2]; \
        L2(a2r0_, a2i0_, o2r0_, o2i0_); \
        L2(a2r1_, a2i1_, o2r1_, o2i1_); \
        float2 tR0[4], tR1[4]; \
        _Pragma("unroll") \
        for (int r = 0; r < 4; ++r) { \
            int m0_ = mrow5[r]; \
            int m1_ = (m0_ + prow5[r]) & 511; \
            tR0[r] = tw[m0_ + (m0_ >> 4)]; \
            tR1[r] = tw[m1_ + (m1_ >> 4)]; \
            mrow5[r] = (m1_ + prow5[r]) & 511; \
        } \
        float v0_, v1_; \
        EPI(o2r0_, o2i0_, tR0, v0_); \
        EPI(o2r1_, o2i1_, tR1, v1_); \
        if (lane < 32) { \
            float* o_ = out + (b * 256 + (s0)) * 256 + n * 32 + (lane & 31); \
            atomicAdd(o_, v0_); \
            atomicAdd(o_ + 256, v1_); \
        } \
    } while (0)

    if (tk.jump_s == 256) {
        // ---- mega2 P=512 wave: 2 chunks, one output row (t=255), one atomic ----
        float acc = 0.f;
        for (int nc = 0; nc < 2; ++nc) {
            int cb_ = (tk.c16 + nc) * 16;
            pA5 = (cb_ + l15) & 511;
            #pragma unroll
            for (int r = 0; r < 4; ++r) {
                prow5[r] = (cb_ + lg * 4 + r) & 511;
                mrow5[r] = (prow5[r] * 255) & 511;
            }
            JUMP_X(256);
            float v_;
            {
                short8v ar_, ai_, a2r_, a2i_;
                SNAP_A(ar_, ai_);
                f32x4 o1r_[2], o1i_[2], o2r_[2], o2i_[2];
                L1(ar_, ai_, o1r_, o1i_);
                REPACK(o1r_, o1i_, a2r_, a2i_);
                L2(a2r_, a2i_, o2r_, o2i_);
                float2 tR[4];
                #pragma unroll
                for (int r = 0; r < 4; ++r) {
                    int mi_ = mrow5[r] + (mrow5[r] >> 4);
                    tR[r] = tw[mi_];
                }
                EPI(o2r_, o2i_, tR, v_);
            }
            acc += v_;
        }
        if (lane < 32)
            atomicAdd(out + (b * 256 + 255) * 256 + n * 32 + (lane & 31), acc);
        return;
    }

    int cbase = tk.c16 * 16;
    pA5 = ((cbase + l15) << tk.sh) & 511;
    #pragma unroll
    for (int r = 0; r < 4; ++r) {
        prow5[r] = ((cbase + lg * 4 + r) << tk.sh) & 511;
        mrow5[r] = (prow5[r] * tk.t_lo) & 511;
    }

    if (tk.jump_s > 0) {
        JUMP_X(tk.jump_s);                    // covers s < t_lo
        mA5 = (pA5 * tk.jump_s) & 511;        // first update at s = t_lo
    } else {
        for (int s = 0; s < tk.t_lo; ++s) UPDATE_X(s);
    }

    int s = tk.t_lo;
    while (s + 1 <= tk.t_hi) {
        STEP2(s);
        s += 2;
    }
    if (s <= tk.t_hi) {
        STEP1(s, true);
    }
}

extern "C" void kernel_launch(void* const* d_in, const int* in_sizes, int n_in,
                              void* d_out, int out_size, void* d_ws, size_t ws_size,
                              hipStream_t stream) {
    const float* x  = (const float*)d_in[0];
    const float* w1 = (const float*)d_in[1];
    const float* b1 = (const float*)d_in[2];
    const float* w2 = (const float*)d_in[3];
    const float* b2 = (const float*)d_in[4];
    float* out = (float*)d_out;

    // out = x (the "+ x" residual), then the main kernel atomically accumulates.
    hipMemcpyAsync(out, x, (size_t)(4 * 256 * 256) * sizeof(float),
                   hipMemcpyDeviceToDevice, stream);
    hipLaunchKernelGGL(afno_mfma, dim3(1504), dim3(256), 0, stream,
                       x, w1, b1, w2, b2, out);
}

// Round 23
// 57.059 us; speedup vs baseline: 1.0692x; 1.0692x over previous
//
#include <hip/hip_runtime.h>
#include <math.h>

#define LAM 0.01f

typedef __bf16 bf16x8 __attribute__((ext_vector_type(8)));
typedef float f32x4 __attribute__((ext_vector_type(4)));
typedef short short8v __attribute__((ext_vector_type(8)));
typedef short short4v __attribute__((ext_vector_type(4)));

#define BF(v) __builtin_bit_cast(bf16x8, (v))
#define MFMA __builtin_amdgcn_mfma_f32_16x16x32_bf16
#define XROW 36   // xs row stride in shorts (72B): lg-groups land 2-way (free)
#define LDS_FENCE() do { asm volatile("s_waitcnt lgkmcnt(0)" ::: "memory"); \
                         __builtin_amdgcn_sched_barrier(0); } while (0)

__device__ __forceinline__ unsigned short f2bf(float f) {
    __bf16 h = (__bf16)f;
    return __builtin_bit_cast(unsigned short, h);
}
__device__ __forceinline__ float bf2f(unsigned short u) {
    unsigned int v = ((unsigned int)u) << 16;
    return __builtin_bit_cast(float, v);
}

// 188 wave-tasks/(b,n), tau = (block_w<<2)|wv. sh = 9-log2(P); twiddles in
// 512-space. jump_s is EXCLUSIVE of t_lo (covers s < t_lo): every steady step
// does an update -> uniform 8 STEP2 pairs per 16-step segment.
// Mega P=512 tasks cover 2 chunks each (16 tasks).
struct Task { int sh, c16, t_lo, t_hi, jump_s; };
__device__ __forceinline__ Task task_params(int tau) {
    Task tk;
    if (tau < 16)       { tk.sh = 0; tk.c16 = tau * 2; tk.t_lo = 255; tk.t_hi = 255; tk.jump_s = 256; }   // P=512 mega2
    else if (tau < 144) { int u = tau - 16;  int seg = u >> 4; tk.sh = 1; tk.c16 = u & 15;
                          tk.t_lo = 127 + 16 * seg; tk.t_hi = tk.t_lo + 15; tk.jump_s = tk.t_lo; }        // P=256
    else if (tau < 176) { int u = tau - 144; int seg = u >> 3; tk.sh = 2; tk.c16 = u & 7;
                          tk.t_lo = 63 + 16 * seg; tk.t_hi = tk.t_lo + 15; tk.jump_s = tk.t_lo; }         // P=128
    else if (tau < 184) { int u = tau - 176; int seg = u >> 2; tk.sh = 3; tk.c16 = u & 3;
                          tk.t_lo = 31 + 16 * seg; tk.t_hi = tk.t_lo + 15; tk.jump_s = tk.t_lo; }         // P=64
    else if (tau < 186) { tk.sh = 4; tk.c16 = tau - 184; tk.t_lo = 15; tk.t_hi = 30; tk.jump_s = 0; }     // P=32
    else if (tau == 186){ tk.sh = 5; tk.c16 = 0; tk.t_lo = 7; tk.t_hi = 14; tk.jump_s = 0; }              // P=16
    else                { tk.sh = 6; tk.c16 = 0; tk.t_lo = 0; tk.t_hi = 6;  tk.jump_s = 0; }              // P=8
    return tk;
}

// MFMA layouts (m89-verified). Layer1 transposed; layer-1 output channels
// permuted so C regs ARE the layer-2 A-fragment (r10). STEP2 = 2 independent
// fence-free chains (r19 sweet spot; STEP4 spilled r20; hand cvt_pk regressed
// r22 -- compiler packing wins). invSqrtP folded into W1 fwd / W2+b2 inv
// (softshrink(ax,aL)=a*softshrink(x,L)). launch_bounds(256,3): (256,4)
// spilled (r10). Spill tell = WRITE_SIZE >> 16MB.
__global__ __launch_bounds__(256, 3)
void afno_mfma(const float* __restrict__ x,
               const float* __restrict__ w1,
               const float* __restrict__ b1,
               const float* __restrict__ w2,
               const float* __restrict__ b2,
               float* __restrict__ out) {
    __shared__ unsigned short xs[256 * XROW];  // raw bf16 x, stride-padded  18 KB
    __shared__ float2 tw[544];                 // (cos,sin)(2pi m/512), idx m+(m>>4)
    __shared__ float jslab[4 * 544];           // per-wave f32 [16][33] jump slab

    int bid = blockIdx.x;
    int w  = bid >> 5;                    // 0..46
    int bn = bid & 31;
    int b = bn >> 3, n = bn & 7;

    int tid = threadIdx.x;
    int wv = tid >> 6;
    int lane = tid & 63;
    int lg = lane >> 4;
    int l15 = lane & 15;
    int krow = lg * 8;

    // ---- stage x rows (raw bf16, rows padded to a 32-multiple) + twiddles ----
    int rows = 0;
    #pragma unroll
    for (int q = 0; q < 4; ++q) {
        Task t2 = task_params((w << 2) | q);
        rows = rows > (t2.t_hi + 1) ? rows : (t2.t_hi + 1);
    }
    rows = (rows + 31) & ~31;
    rows = rows > 256 ? 256 : rows;
    for (int idx = tid; idx < rows * 16; idx += 256) {
        int row = idx >> 4, cp = idx & 15;
        float2 v = *(const float2*)(x + (b * 256 + row) * 256 + n * 32 + cp * 2);
        unsigned int pk = (unsigned int)f2bf(v.x) | ((unsigned int)f2bf(v.y) << 16);
        *(unsigned int*)(xs + row * XROW + cp * 2) = pk;
    }
    for (int m = tid; m < 512; m += 256) {
        float sv, cv;
        sincosf(6.28318530717958647692f * (float)m * (1.0f / 512.0f), &sv, &cv);
        tw[m + (m >> 4)] = make_float2(cv, sv);
    }

    Task tk = task_params((w << 2) | wv);
    int P = 512 >> tk.sh;
    float invSqrtP = rsqrtf((float)P);
    float LAMe = LAM * invSqrtP;          // effective softshrink threshold

    // ---- weights -> bf16 fragments; W1 carries forward 1/sqrt(P), W2/b2 carry
    //      inverse 1/sqrt(P); W2 rows in chan-permuted order ----
    const float* w1r = w1 + n * 1024;
    const float* w1i = w1 + (8 + n) * 1024;
    const float* w2r = w2 + n * 1024;
    const float* w2i = w2 + (8 + n) * 1024;
    short8v W10[2], W11[2], W11n[2], W20[2], W21[2], W21n[2];
    #pragma unroll
    for (int h = 0; h < 2; ++h) {
        int col = h * 16 + l15;
        #pragma unroll
        for (int j = 0; j < 8; ++j) {
            W10[h][j]  = (short)f2bf(w1r[(krow + j) * 32 + col] * invSqrtP);
            W11[h][j]  = (short)f2bf(w1i[(krow + j) * 32 + col] * invSqrtP);
            W11n[h][j] = W11[h][j] ^ (short)0x8000;
            int crow = ((j >> 2) * 16) + (lg * 4) + (j & 3);   // chan permutation
            W20[h][j]  = (short)f2bf(w2r[crow * 32 + col] * invSqrtP);
            W21[h][j]  = (short)f2bf(w2i[crow * 32 + col] * invSqrtP);
            W21n[h][j] = W21[h][j] ^ (short)0x8000;
        }
    }
    f32x4 b1rv[2], b1iv[2];
    float b2r_[2], b2i_[2];
    #pragma unroll
    for (int h = 0; h < 2; ++h) {
        int base = n * 32 + h * 16 + lg * 4;
        b1rv[h] = f32x4{b1[base], b1[base + 1], b1[base + 2], b1[base + 3]};
        b1iv[h] = f32x4{b1[256 + base], b1[256 + base + 1], b1[256 + base + 2], b1[256 + base + 3]};
        b2r_[h] = b2[n * 32 + h * 16 + l15] * invSqrtP;
        b2i_[h] = b2[256 + n * 32 + h * 16 + l15] * invSqrtP;
    }
    __syncthreads();   // only block barrier

    int pA5 = 0, mA5 = 0;
    int prow5[4], mrow5[4];
    float Xre[8] = {0,0,0,0,0,0,0,0}, Xim[8] = {0,0,0,0,0,0,0,0};

// Prefix jump via MFMA: X = sum_{s < js_} e^{-i th} x[s]. Per-j validity mask.
#define JUMP_X(js_) do { \
        f32x4 jre0 = {0,0,0,0}, jre1 = {0,0,0,0}, jim0 = {0,0,0,0}, jim1 = {0,0,0,0}; \
        int nkk_ = ((js_) + 31) >> 5; \
        for (int kk = 0; kk < nkk_; ++kk) { \
            int sb_ = kk * 32; \
            short8v ac_, an2_; \
            int mj_ = (pA5 * (sb_ + krow)) & 511; \
            _Pragma("unroll") \
            for (int j = 0; j < 8; ++j) { \
                int mi2_ = mj_ + (mj_ >> 4); \
                float2 t_ = tw[mi2_]; \
                bool ok_ = (sb_ + krow + j) < (js_); \
                ac_[j]  = ok_ ? (short)f2bf(t_.x)  : (short)0; \
                an2_[j] = ok_ ? (short)f2bf(-t_.y) : (short)0; \
                mj_ = (mj_ + pA5) & 511; \
            } \
            short8v bx0_, bx1_; \
            _Pragma("unroll") \
            for (int j = 0; j < 8; ++j) { \
                int base_ = (sb_ + krow + j) * XROW + l15; \
                bx0_[j] = (short)xs[base_]; \
                bx1_[j] = (short)xs[base_ + 16]; \
            } \
            jre0 = MFMA(BF(ac_),  BF(bx0_), jre0, 0, 0, 0); \
            jim0 = MFMA(BF(an2_), BF(bx0_), jim0, 0, 0, 0); \
            jre1 = MFMA(BF(ac_),  BF(bx1_), jre1, 0, 0, 0); \
            jim1 = MFMA(BF(an2_), BF(bx1_), jim1, 0, 0, 0); \
        } \
        float* jt_ = jslab + wv * 544; \
        _Pragma("unroll") \
        for (int r = 0; r < 4; ++r) { \
            jt_[(lg * 4 + r) * 33 + l15]      = jre0[r]; \
            jt_[(lg * 4 + r) * 33 + 16 + l15] = jre1[r]; \
        } \
        LDS_FENCE(); \
        _Pragma("unroll") \
        for (int j = 0; j < 8; ++j) Xre[j] = jt_[l15 * 33 + krow + j]; \
        LDS_FENCE(); \
        _Pragma("unroll") \
        for (int r = 0; r < 4; ++r) { \
            jt_[(lg * 4 + r) * 33 + l15]      = jim0[r]; \
            jt_[(lg * 4 + r) * 33 + 16 + l15] = jim1[r]; \
        } \
        LDS_FENCE(); \
        _Pragma("unroll") \
        for (int j = 0; j < 8; ++j) Xim[j] = jt_[l15 * 33 + krow + j]; \
        LDS_FENCE(); \
    } while (0)

#define UPDATE_X(sidx) do { \
        int mi_ = mA5 + (mA5 >> 4); \
        float2 t_ = tw[mi_]; \
        mA5 = (mA5 + pA5) & 511; \
        short4v xa_ = *(const short4v*)(xs + (sidx) * XROW + krow); \
        short4v xb_ = *(const short4v*)(xs + (sidx) * XROW + krow + 4); \
        _Pragma("unroll") \
        for (int j = 0; j < 4; ++j) { \
            float xf = bf2f((unsigned short)xa_[j]); \
            Xre[j] = fmaf(xf, t_.x, Xre[j]); \
            Xim[j] = fmaf(xf, -t_.y, Xim[j]); \
            float xg = bf2f((unsigned short)xb_[j]); \
            Xre[4 + j] = fmaf(xg, t_.x, Xre[4 + j]); \
            Xim[4 + j] = fmaf(xg, -t_.y, Xim[4 + j]); \
        } } while (0)

#define SNAP_A(arv, aiv) do { \
        _Pragma("unroll") \
        for (int j = 0; j < 8; ++j) { \
            (arv)[j] = (short)f2bf(Xre[j]); \
            (aiv)[j] = (short)f2bf(Xim[j]); \
        } } while (0)

#define L1(arv, aiv, o1r_, o1i_) do { \
        _Pragma("unroll") \
        for (int h = 0; h < 2; ++h) { \
            o1r_[h] = MFMA(BF(arv), BF(W10[h]),  b1rv[h], 0, 0, 0); \
            o1r_[h] = MFMA(BF(aiv), BF(W11n[h]), o1r_[h], 0, 0, 0); \
            o1i_[h] = MFMA(BF(aiv), BF(W10[h]),  b1iv[h], 0, 0, 0); \
            o1i_[h] = MFMA(BF(arv), BF(W11[h]),  o1i_[h], 0, 0, 0); \
        } } while (0)

#define REPACK(o1r_, o1i_, a2r_, a2i_) do { \
        _Pragma("unroll") \
        for (int j = 0; j < 8; ++j) { \
            (a2r_)[j] = (short)f2bf(fmaxf(o1r_[j >> 2][j & 3], 0.f)); \
            (a2i_)[j] = (short)f2bf(fmaxf(o1i_[j >> 2][j & 3], 0.f)); \
        } } while (0)

#define L2(a2r_, a2i_, o2r_, o2i_) do { \
        _Pragma("unroll") \
        for (int h = 0; h < 2; ++h) { \
            f32x4 cr = {b2r_[h], b2r_[h], b2r_[h], b2r_[h]}; \
            f32x4 ci = {b2i_[h], b2i_[h], b2i_[h], b2i_[h]}; \
            o2r_[h] = MFMA(BF(a2r_), BF(W20[h]),  cr, 0, 0, 0); \
            o2r_[h] = MFMA(BF(a2i_), BF(W21n[h]), o2r_[h], 0, 0, 0); \
            o2i_[h] = MFMA(BF(a2i_), BF(W20[h]),  ci, 0, 0, 0); \
            o2i_[h] = MFMA(BF(a2r_), BF(W21[h]),  o2i_[h], 0, 0, 0); \
        } } while (0)

// epilogue (softshrink with LAMe; inverse norm pre-folded into W2/b2)
#define EPI(o2r_, o2i_, tR, DEST) do { \
        float sh0 = 0.f, sh1 = 0.f; \
        _Pragma("unroll") \
        for (int r = 0; r < 4; ++r) { \
            float v0r = o2r_[0][r]; v0r -= __builtin_amdgcn_fmed3f(v0r, -LAMe, LAMe); \
            float v0i = o2i_[0][r]; v0i -= __builtin_amdgcn_fmed3f(v0i, -LAMe, LAMe); \
            sh0 = fmaf(v0r, (tR)[r].x, sh0); sh0 = fmaf(-v0i, (tR)[r].y, sh0); \
            float v1r = o2r_[1][r]; v1r -= __builtin_amdgcn_fmed3f(v1r, -LAMe, LAMe); \
            float v1i = o2i_[1][r]; v1i -= __builtin_amdgcn_fmed3f(v1i, -LAMe, LAMe); \
            sh1 = fmaf(v1r, (tR)[r].x, sh1); sh1 = fmaf(-v1i, (tR)[r].y, sh1); \
        } \
        sh0 += __shfl_xor(sh0, 16); \
        sh1 += __shfl_xor(sh1, 16); \
        if (P > 8) { sh0 += __shfl_xor(sh0, 32); sh1 += __shfl_xor(sh1, 32); } \
        DEST = (lane & 16) ? sh1 : sh0; \
    } while (0)

#define STEP1(sidx, do_upd) do { \
        if (do_upd) UPDATE_X(sidx); \
        short8v ar_, ai_, a2r_, a2i_; \
        SNAP_A(ar_, ai_); \
        f32x4 o1r_[2], o1i_[2], o2r_[2], o2i_[2]; \
        L1(ar_, ai_, o1r_, o1i_); \
        REPACK(o1r_, o1i_, a2r_, a2i_); \
        L2(a2r_, a2i_, o2r_, o2i_); \
        float2 tR[4]; \
        _Pragma("unroll") \
        for (int r = 0; r < 4; ++r) { \
            int mi_ = mrow5[r] + (mrow5[r] >> 4); \
            tR[r] = tw[mi_]; \
            mrow5[r] = (mrow5[r] + prow5[r]) & 511; \
        } \
        float v_; \
        EPI(o2r_, o2i_, tR, v_); \
        if (lane < 32) \
            atomicAdd(out + (b * 256 + (sidx)) * 256 + n * 32 + (lane & 31), v_); \
    } while (0)

// two independent chains, fence-free; atomics at the end (r19 sweet spot)
#define STEP2(s0) do { \
        short8v ar0_, ai0_, ar1_, ai1_, a2r0_, a2i0_, a2r1_, a2i1_; \
        UPDATE_X(s0);     SNAP_A(ar0_, ai0_); \
        UPDATE_X((s0)+1); SNAP_A(ar1_, ai1_); \
        f32x4 o1r0_[2], o1i0_[2], o1r1_[2], o1i1_[2]; \
        L1(ar0_, ai0_, o1r0_, o1i0_); \
        L1(ar1_, ai1_, o1r1_, o1i1_); \
        REPACK(o1r0_, o1i0_, a2r0_, a2i0_); \
        REPACK(o1r1_, o1i1_, a2r1_, a2i1_); \
        f32x4 o2r0_[2], o2i0_[2], o2r1_[2], o2i1_[2]; \
        L2(a2r0_, a2i0_, o2r0_, o2i0_); \
        L2(a2r1_, a2i1_, o2r1_, o2i1_); \
        float2 tR0[4], tR1[4]; \
        _Pragma("unroll") \
        for (int r = 0; r < 4; ++r) { \
            int m0_ = mrow5[r]; \
            int m1_ = (m0_ + prow5[r]) & 511; \
            tR0[r] = tw[m0_ + (m0_ >> 4)]; \
            tR1[r] = tw[m1_ + (m1_ >> 4)]; \
            mrow5[r] = (m1_ + prow5[r]) & 511; \
        } \
        float v0_, v1_; \
        EPI(o2r0_, o2i0_, tR0, v0_); \
        EPI(o2r1_, o2i1_, tR1, v1_); \
        if (lane < 32) { \
            float* o_ = out + (b * 256 + (s0)) * 256 + n * 32 + (lane & 31); \
            atomicAdd(o_, v0_); \
            atomicAdd(o_ + 256, v1_); \
        } \
    } while (0)

    if (tk.jump_s == 256) {
        // ---- mega2 P=512 wave: 2 chunks, one output row (t=255), one atomic ----
        float acc = 0.f;
        for (int nc = 0; nc < 2; ++nc) {
            int cb_ = (tk.c16 + nc) * 16;
            pA5 = (cb_ + l15) & 511;
            #pragma unroll
            for (int r = 0; r < 4; ++r) {
                prow5[r] = (cb_ + lg * 4 + r) & 511;
                mrow5[r] = (prow5[r] * 255) & 511;
            }
            JUMP_X(256);
            float v_;
            {
                short8v ar_, ai_, a2r_, a2i_;
                SNAP_A(ar_, ai_);
                f32x4 o1r_[2], o1i_[2], o2r_[2], o2i_[2];
                L1(ar_, ai_, o1r_, o1i_);
                REPACK(o1r_, o1i_, a2r_, a2i_);
                L2(a2r_, a2i_, o2r_, o2i_);
                float2 tR[4];
                #pragma unroll
                for (int r = 0; r < 4; ++r) {
                    int mi_ = mrow5[r] + (mrow5[r] >> 4);
                    tR[r] = tw[mi_];
                }
                EPI(o2r_, o2i_, tR, v_);
            }
            acc += v_;
        }
        if (lane < 32)
            atomicAdd(out + (b * 256 + 255) * 256 + n * 32 + (lane & 31), acc);
        return;
    }

    int cbase = tk.c16 * 16;
    pA5 = ((cbase + l15) << tk.sh) & 511;
    #pragma unroll
    for (int r = 0; r < 4; ++r) {
        prow5[r] = ((cbase + lg * 4 + r) << tk.sh) & 511;
        mrow5[r] = (prow5[r] * tk.t_lo) & 511;
    }

    if (tk.jump_s > 0) {
        JUMP_X(tk.jump_s);                    // covers s < t_lo
        mA5 = (pA5 * tk.jump_s) & 511;        // first update at s = t_lo
    } else {
        for (int s = 0; s < tk.t_lo; ++s) UPDATE_X(s);
    }

    int s = tk.t_lo;
    while (s + 1 <= tk.t_hi) {
        STEP2(s);
        s += 2;
    }
    if (s <= tk.t_hi) {
        STEP1(s, true);
    }
}

extern "C" void kernel_launch(void* const* d_in, const int* in_sizes, int n_in,
                              void* d_out, int out_size, void* d_ws, size_t ws_size,
                              hipStream_t stream) {
    const float* x  = (const float*)d_in[0];
    const float* w1 = (const float*)d_in[1];
    const float* b1 = (const float*)d_in[2];
    const float* w2 = (const float*)d_in[3];
    const float* b2 = (const float*)d_in[4];
    float* out = (float*)d_out;

    // out = x (the "+ x" residual), then the main kernel atomically accumulates.
    hipMemcpyAsync(out, x, (size_t)(4 * 256 * 256) * sizeof(float),
                   hipMemcpyDeviceToDevice, stream);
    hipLaunchKernelGGL(afno_mfma, dim3(1504), dim3(256), 0, stream,
                       x, w1, b1, w2, b2, out);
}